// Round 1
// baseline (7854.101 us; speedup 1.0000x reference)
//
#include <hip/hip_runtime.h>
#include <hip/hip_bf16.h>

typedef unsigned short u16;
using short8 = __attribute__((ext_vector_type(8))) short;
using f32x4  = __attribute__((ext_vector_type(4))) float;

#define DEVINL static __device__ __forceinline__

DEVINL float bf2f(u16 u){
  union { unsigned int i; float f; } x; x.i = ((unsigned int)u) << 16; return x.f;
}
DEVINL u16 f2bf(float f){
  union { float f; unsigned int i; } x; x.f = f;
  unsigned int i = x.i;
  return (u16)((i + 0x7FFFu + ((i >> 16) & 1u)) >> 16);
}
DEVINL float sigm(float x){ return 1.f / (1.f + __expf(-x)); }
DEVINL float tanhf_(float x){
  x = fminf(fmaxf(x, -20.f), 20.f);
  float e = __expf(-2.f * x);
  return (1.f - e) / (1.f + e);
}
DEVINL f32x4 zero4(){ f32x4 z = {0.f, 0.f, 0.f, 0.f}; return z; }

DEVINL f32x4 mfma16(short8 a, short8 b, f32x4 c){
  return __builtin_amdgcn_mfma_f32_16x16x32_bf16(a, b, c, 0, 0, 0);
}

// lane l: row = l&15, k0 = (l>>4)*8 ; 16B vector read. stride in elements, rows 16B-aligned.
DEVINL short8 frag_ld(const u16* base, int stride){
  int l = threadIdx.x & 63;
  return *(const short8*)(base + (l & 15) * stride + ((l >> 4) << 3));
}

// C = A(16xK) * W(NxK)^T for N-tile nt. K multiple of 32 (padded). strides = Kp+8.
DEVINL f32x4 tile_mm(const u16* A, int strideA, const u16* W, int strideW, int K, int nt){
  f32x4 acc = {0.f, 0.f, 0.f, 0.f};
  const u16* wrow = W + nt * 16 * strideW;
  #pragma unroll
  for (int ks = 0; ks < K; ks += 32){
    short8 a = frag_ld(A + ks, strideA);
    short8 b = frag_ld(wrow + ks, strideW);
    acc = mfma16(a, b, acc);
  }
  return acc;
}

// acc layout: col = lane&15 (+col_base), rows = (lane>>4)*4 + r
DEVINL void acc_store_lds(u16* dst, int stride, int col_base, f32x4 acc, float bias, bool relu){
  int l = threadIdx.x & 63;
  int col = col_base + (l & 15);
  int row0 = (l >> 4) * 4;
  #pragma unroll
  for (int r = 0; r < 4; r++){
    float v = acc[r] + bias;
    if (relu) v = fmaxf(v, 0.f);
    dst[(row0 + r) * stride + col] = f2bf(v);
  }
}
DEVINL void acc_store_g(u16* dst, int stride, int col_base, f32x4 acc, float bias, bool relu){
  int l = threadIdx.x & 63;
  int col = col_base + (l & 15);
  int row0 = (l >> 4) * 4;
  #pragma unroll
  for (int r = 0; r < 4; r++){
    float v = acc[r] + bias;
    if (relu) v = fmaxf(v, 0.f);
    dst[(size_t)(row0 + r) * stride + col] = f2bf(v);
  }
}

// stage fp32 (N,K) row-major weights -> bf16 LDS [N][Kp+8]; zero cols K..Kp
DEVINL void stage_weights(u16* dst, const float* src, int N, int K, int Kp){
  int stride = Kp + 8;
  if (Kp > K){
    int padw = Kp - K;
    for (int i = threadIdx.x; i < N * padw; i += blockDim.x){
      int n = i / padw, k = K + (i - (i / padw) * padw);
      dst[n * stride + k] = 0;
    }
  }
  for (int i = threadIdx.x * 4; i < N * K; i += blockDim.x * 4){
    float4 v = *(const float4*)(src + i);
    int n = i / K, k = i - n * K;
    u16* d = dst + n * stride + k;
    d[0] = f2bf(v.x); d[1] = f2bf(v.y); d[2] = f2bf(v.z); d[3] = f2bf(v.w);
  }
}

__global__ __launch_bounds__(256) void k_inith(const float* __restrict__ h0, u16* __restrict__ hst){
  int i = blockIdx.x * 256 + threadIdx.x;
  if (i < 2 * 1024 * 128) hst[i] = f2bf(h0[i]);
}

// ---------------- phase A1: phi_u = relu(u_t @ w0^T + b0) @ w1^T + b1 ----------------
__global__ __launch_bounds__(512) void k_phiu(const float* __restrict__ u,
    const float* __restrict__ w0, const float* __restrict__ b0,
    const float* __restrict__ w1, const float* __restrict__ b1,
    u16* __restrict__ phi, int t0, int Tc){
  __shared__ __align__(16) u16 w0s[128 * 40];
  __shared__ __align__(16) u16 w1s[128 * 136];
  __shared__ __align__(16) u16 uts[16 * 40];
  __shared__ __align__(16) u16 hid[16 * 136];
  stage_weights(w0s, w0, 128, 16, 32);
  stage_weights(w1s, w1, 128, 128, 128);
  for (int i = threadIdx.x; i < 16 * 40; i += blockDim.x) uts[i] = 0;
  int wv = threadIdx.x >> 6, l = threadIdx.x & 63;
  float bias0 = b0[wv * 16 + (l & 15)];
  float bias1 = b1[wv * 16 + (l & 15)];
  __syncthreads();
  int tpb = Tc >> 4;
  int ntile = 1024 * tpb;
  for (int tile = blockIdx.x; tile < ntile; tile += gridDim.x){
    int b = tile / tpb;
    int tt = (tile - b * tpb) << 4;
    if (threadIdx.x < 256){
      int k = threadIdx.x >> 4, t = threadIdx.x & 15;
      uts[t * 40 + k] = f2bf(u[(b * 16 + k) * 1024 + t0 + tt + t]);
    }
    __syncthreads();
    f32x4 a1 = tile_mm(uts, 40, w0s, 40, 32, wv);
    acc_store_lds(hid, 136, wv * 16, a1, bias0, true);
    __syncthreads();
    f32x4 a2 = tile_mm(hid, 136, w1s, 136, 128, wv);
    acc_store_g(phi + (size_t)(b * Tc + tt) * 128, 128, wv * 16, a2, bias1, false);
    __syncthreads();
  }
}

// ---------------- phase A3: gi0 = phi_u @ wih0^T ----------------
__global__ __launch_bounds__(512) void k_gi0(const u16* __restrict__ phi,
    const float* __restrict__ wih0, u16* __restrict__ gi0, int Tc){
  __shared__ __align__(16) u16 wS[384 * 136];
  __shared__ __align__(16) u16 xS[16 * 136];
  stage_weights(wS, wih0, 384, 128, 128);
  int wv = threadIdx.x >> 6;
  __syncthreads();
  int tpb = Tc >> 4;
  int ntile = 1024 * tpb;
  for (int tile = blockIdx.x; tile < ntile; tile += gridDim.x){
    int b = tile / tpb;
    int tt = (tile - b * tpb) << 4;
    size_t rbase = (size_t)(b * Tc + tt);
    {
      int i = threadIdx.x * 4;
      int row = i >> 7, k = i & 127;
      *(uint2*)(xS + row * 136 + k) = *(const uint2*)(phi + rbase * 128 + i);
    }
    __syncthreads();
    #pragma unroll
    for (int s = 0; s < 3; s++){
      int nt = s * 8 + wv;
      f32x4 acc = tile_mm(xS, 136, wS, 136, 128, nt);
      acc_store_g(gi0 + rbase * 384, 384, nt * 16, acc, 0.f, false);
    }
    __syncthreads();
  }
}

// ---------------- phase B: sequential 2-layer GRU, weights stationary in registers ----------------
__global__ __launch_bounds__(512) void k_gru(const u16* __restrict__ gi0,
    const float* __restrict__ gwhh, const float* __restrict__ gwih,
    u16* __restrict__ hst, u16* __restrict__ Hs, int Tc){
  __shared__ __align__(16) u16 h0s[16 * 136];
  __shared__ __align__(16) u16 h1s[16 * 136];
  int wv = threadIdx.x >> 6, l = threadIdx.x & 63;
  int b0 = blockIdx.x * 16;
  const float* srcs[3] = { gwhh, gwih + 384 * 128, gwhh + 384 * 128 }; // whh0, wih1, whh1
  short8 wB[3][3][4];
  #pragma unroll
  for (int mm = 0; mm < 3; mm++){
    #pragma unroll
    for (int g = 0; g < 3; g++){
      int n = g * 128 + wv * 16 + (l & 15);
      #pragma unroll
      for (int ks = 0; ks < 4; ks++){
        const float* p = srcs[mm] + n * 128 + ks * 32 + ((l >> 4) << 3);
        float4 va = *(const float4*)p;
        float4 vb = *(const float4*)(p + 4);
        short8 f;
        f[0] = (short)f2bf(va.x); f[1] = (short)f2bf(va.y);
        f[2] = (short)f2bf(va.z); f[3] = (short)f2bf(va.w);
        f[4] = (short)f2bf(vb.x); f[5] = (short)f2bf(vb.y);
        f[6] = (short)f2bf(vb.z); f[7] = (short)f2bf(vb.w);
        wB[mm][g][ks] = f;
      }
    }
  }
  // restore state (bf16) into padded LDS
  for (int i = threadIdx.x * 4; i < 4096; i += 2048){
    int layer = i >> 11, j = i & 2047;
    int row = j >> 7, k = j & 127;
    u16* dst = (layer ? h1s : h0s) + row * 136 + k;
    *(uint2*)dst = *(const uint2*)(hst + layer * 131072 + (b0 + row) * 128 + k);
  }
  __syncthreads();
  // H[t=0 of this chunk] = current h1
  for (int i = threadIdx.x * 4; i < 2048; i += 2048){
    int row = i >> 7, k = i & 127;
    *(uint2*)(Hs + (size_t)(b0 + row) * Tc * 128 + k) = *(const uint2*)(h1s + row * 136 + k);
  }

  int m0 = (l >> 4) * 4;
  int colw = wv * 16 + (l & 15);
  float gcur[3][4];
  #pragma unroll
  for (int g = 0; g < 3; g++)
    #pragma unroll
    for (int r = 0; r < 4; r++)
      gcur[g][r] = bf2f(gi0[((size_t)(b0 + m0 + r) * Tc) * 384 + g * 128 + colw]);

  for (int tl = 0; tl < Tc; tl++){
    float gnxt[3][4];
    #pragma unroll
    for (int g = 0; g < 3; g++)
      #pragma unroll
      for (int r = 0; r < 4; r++)
        gnxt[g][r] = (tl + 1 < Tc)
          ? bf2f(gi0[((size_t)(b0 + m0 + r) * Tc + tl + 1) * 384 + g * 128 + colw]) : 0.f;

    float h0p[4], h1p[4];
    #pragma unroll
    for (int r = 0; r < 4; r++){
      h0p[r] = bf2f(h0s[(m0 + r) * 136 + colw]);
      h1p[r] = bf2f(h1s[(m0 + r) * 136 + colw]);
    }
    short8 a[4];
    f32x4 gh0[3], gh1[3];
    #pragma unroll
    for (int g = 0; g < 3; g++){ gh0[g] = zero4(); gh1[g] = zero4(); }
    #pragma unroll
    for (int ks = 0; ks < 4; ks++) a[ks] = frag_ld(h0s + ks * 32, 136);
    #pragma unroll
    for (int g = 0; g < 3; g++)
      #pragma unroll
      for (int ks = 0; ks < 4; ks++)
        gh0[g] = mfma16(a[ks], wB[0][g][ks], gh0[g]);
    #pragma unroll
    for (int ks = 0; ks < 4; ks++) a[ks] = frag_ld(h1s + ks * 32, 136);
    #pragma unroll
    for (int g = 0; g < 3; g++)
      #pragma unroll
      for (int ks = 0; ks < 4; ks++)
        gh1[g] = mfma16(a[ks], wB[2][g][ks], gh1[g]);

    float h0n[4];
    #pragma unroll
    for (int r = 0; r < 4; r++){
      float rg = sigm(gcur[0][r] + gh0[0][r]);
      float zg = sigm(gcur[1][r] + gh0[1][r]);
      float ng = tanhf_(gcur[2][r] + rg * gh0[2][r]);
      h0n[r] = (1.f - zg) * ng + zg * h0p[r];
    }
    __syncthreads();   // all reads of h0s/h1s done
    #pragma unroll
    for (int r = 0; r < 4; r++)
      h0s[(m0 + r) * 136 + colw] = f2bf(h0n[r]);
    __syncthreads();   // new h0 visible

    f32x4 gi1[3];
    #pragma unroll
    for (int g = 0; g < 3; g++) gi1[g] = zero4();
    #pragma unroll
    for (int ks = 0; ks < 4; ks++) a[ks] = frag_ld(h0s + ks * 32, 136);
    #pragma unroll
    for (int g = 0; g < 3; g++)
      #pragma unroll
      for (int ks = 0; ks < 4; ks++)
        gi1[g] = mfma16(a[ks], wB[1][g][ks], gi1[g]);

    #pragma unroll
    for (int r = 0; r < 4; r++){
      float rg = sigm(gi1[0][r] + gh1[0][r]);
      float zg = sigm(gi1[1][r] + gh1[1][r]);
      float ng = tanhf_(gi1[2][r] + rg * gh1[2][r]);
      float hn = (1.f - zg) * ng + zg * h1p[r];
      u16 v = f2bf(hn);
      h1s[(m0 + r) * 136 + colw] = v;
      if (tl + 1 < Tc) Hs[((size_t)(b0 + m0 + r) * Tc + tl + 1) * 128 + colw] = v;
    }
    #pragma unroll
    for (int g = 0; g < 3; g++)
      #pragma unroll
      for (int r = 0; r < 4; r++)
        gcur[g][r] = gnxt[g][r];
    __syncthreads();   // h writes visible for next step
  }
  // save state
  for (int i = threadIdx.x * 4; i < 4096; i += 2048){
    int layer = i >> 11, j = i & 2047;
    int row = j >> 7, k = j & 127;
    const u16* src = (layer ? h1s : h0s) + row * 136 + k;
    *(uint2*)(hst + layer * 131072 + (b0 + row) * 128 + k) = *(const uint2*)src;
  }
}

// ---------------- phase C1: dphi = mlp2([phi_u, h1_prev]); x_mean/x_logvar ----------------
__global__ __launch_bounds__(512) void k_c1(const u16* __restrict__ phi, const u16* __restrict__ Hs,
    const float* __restrict__ dw0, const float* __restrict__ db0,
    const float* __restrict__ dw1, const float* __restrict__ db1,
    const float* __restrict__ xmw, const float* __restrict__ xmb,
    const float* __restrict__ xlw, const float* __restrict__ xlb,
    u16* __restrict__ xmlv, int Tc){
  __shared__ __align__(16) u16 w0s[128 * 264];
  __shared__ __align__(16) u16 w1s[128 * 136];
  __shared__ __align__(16) u16 xws[32 * 136];
  __shared__ __align__(16) u16 ins[16 * 264];
  __shared__ __align__(16) u16 d1s[16 * 136];
  __shared__ __align__(16) u16 d2s[16 * 136];
  stage_weights(w0s, dw0, 128, 256, 256);
  stage_weights(w1s, dw1, 128, 128, 128);
  stage_weights(xws, xmw, 16, 128, 128);
  stage_weights(xws + 16 * 136, xlw, 16, 128, 128);
  int wv = threadIdx.x >> 6, l = threadIdx.x & 63;
  float bias0 = db0[wv * 16 + (l & 15)];
  float bias1 = db1[wv * 16 + (l & 15)];
  float biasx = (wv == 0) ? xmb[l & 15] : ((wv == 1) ? xlb[l & 15] : 0.f);
  __syncthreads();
  int tpb = Tc >> 4;
  int ntile = 1024 * tpb;
  for (int tile = blockIdx.x; tile < ntile; tile += gridDim.x){
    int b = tile / tpb;
    int tt = (tile - b * tpb) << 4;
    size_t rbase = (size_t)(b * Tc + tt);
    {
      int i = threadIdx.x * 4;
      int row = i >> 7, k = i & 127;
      *(uint2*)(ins + row * 264 + k)       = *(const uint2*)(phi + rbase * 128 + i);
      *(uint2*)(ins + row * 264 + 128 + k) = *(const uint2*)(Hs  + rbase * 128 + i);
    }
    __syncthreads();
    f32x4 acc = tile_mm(ins, 264, w0s, 264, 256, wv);
    acc_store_lds(d1s, 136, wv * 16, acc, bias0, true);
    __syncthreads();
    acc = tile_mm(d1s, 136, w1s, 136, 128, wv);
    acc_store_lds(d2s, 136, wv * 16, acc, bias1, false);
    __syncthreads();
    if (wv < 2){
      acc = tile_mm(d2s, 136, xws + wv * 16 * 136, 136, 128, 0);
      acc_store_g(xmlv + rbase * 32, 32, wv * 16, acc, biasx, false);
    }
    __syncthreads();
  }
}

// ---------------- phase C2: phi_x, menn, +x_mean@C^T, loss ----------------
__global__ __launch_bounds__(512) void k_c2(const u16* __restrict__ xmlv, const float* __restrict__ y,
    const float* __restrict__ pw0, const float* __restrict__ pb0,
    const float* __restrict__ pw1, const float* __restrict__ pb1,
    const float* __restrict__ mw0, const float* __restrict__ mb0,
    const float* __restrict__ mw1, const float* __restrict__ mb1,
    const float* __restrict__ Cw, float* __restrict__ out, int t0, int Tc){
  __shared__ __align__(16) u16 pw0s[128 * 40];
  __shared__ __align__(16) u16 pw1s[128 * 136];
  __shared__ __align__(16) u16 mw0s[128 * 136];
  __shared__ __align__(16) u16 mw1s[16 * 136];
  __shared__ __align__(16) u16 Cs[16 * 40];
  __shared__ __align__(16) u16 ins[16 * 40];
  __shared__ __align__(16) u16 t1s[16 * 136];
  __shared__ __align__(16) u16 t2s[16 * 136];
  __shared__ __align__(16) u16 t3s[16 * 136];
  __shared__ float ys[16 * 16];
  stage_weights(pw0s, pw0, 128, 32, 32);
  stage_weights(pw1s, pw1, 128, 128, 128);
  stage_weights(mw0s, mw0, 128, 128, 128);
  stage_weights(mw1s, mw1, 16, 128, 128);
  stage_weights(Cs, Cw, 16, 16, 32);
  int wv = threadIdx.x >> 6, l = threadIdx.x & 63;
  float biasp0 = pb0[wv * 16 + (l & 15)];
  float biasp1 = pb1[wv * 16 + (l & 15)];
  float biasm0 = mb0[wv * 16 + (l & 15)];
  float biasm1 = mb1[l & 15];
  __syncthreads();
  float lacc = 0.f;
  int tpb = Tc >> 4;
  int ntile = 1024 * tpb;
  for (int tile = blockIdx.x; tile < ntile; tile += gridDim.x){
    int b = tile / tpb;
    int tt = (tile - b * tpb) << 4;
    size_t rbase = (size_t)(b * Tc + tt);
    if (threadIdx.x < 128){
      int i = threadIdx.x * 4;
      int row = i >> 5, k = i & 31;
      *(uint2*)(ins + row * 40 + k) = *(const uint2*)(xmlv + rbase * 32 + i);
    }
    if (threadIdx.x < 256){
      int j = threadIdx.x >> 4, tq = threadIdx.x & 15;
      ys[tq * 16 + j] = y[(b * 16 + j) * 1024 + t0 + tt + tq];
    }
    __syncthreads();
    f32x4 acc = tile_mm(ins, 40, pw0s, 40, 32, wv);
    acc_store_lds(t1s, 136, wv * 16, acc, biasp0, true);
    __syncthreads();
    acc = tile_mm(t1s, 136, pw1s, 136, 128, wv);
    acc_store_lds(t2s, 136, wv * 16, acc, biasp1, false);
    __syncthreads();
    acc = tile_mm(t2s, 136, mw0s, 136, 128, wv);
    acc_store_lds(t3s, 136, wv * 16, acc, biasm0, true);
    __syncthreads();
    if (wv == 0){
      f32x4 ay = tile_mm(t3s, 136, mw1s, 136, 128, 0);
      f32x4 ac = tile_mm(ins, 40, Cs, 40, 32, 0);   // Cs zero-padded k>=16 -> only x_mean contributes
      #pragma unroll
      for (int r = 0; r < 4; r++){
        float yh = ay[r] + biasm1 + ac[r];
        int m = (l >> 4) * 4 + r, j = l & 15;
        float d = yh - ys[m * 16 + j];
        lacc += d * d;
      }
    }
    __syncthreads();
  }
  if (wv == 0){
    #pragma unroll
    for (int off = 32; off > 0; off >>= 1)
      lacc += __shfl_down(lacc, off);
    if (l == 0) atomicAdd(out, lacc);
  }
}

extern "C" void kernel_launch(void* const* d_in, const int* in_sizes, int n_in,
                              void* d_out, int out_size, void* d_ws, size_t ws_size,
                              hipStream_t stream){
  const float* u    = (const float*)d_in[0];
  const float* y    = (const float*)d_in[1];
  const float* h0   = (const float*)d_in[2];
  const float* puw0 = (const float*)d_in[3];
  const float* pub0 = (const float*)d_in[4];
  const float* puw1 = (const float*)d_in[5];
  const float* pub1 = (const float*)d_in[6];
  const float* dw0  = (const float*)d_in[7];
  const float* db0  = (const float*)d_in[8];
  const float* dw1  = (const float*)d_in[9];
  const float* db1  = (const float*)d_in[10];
  const float* xmw  = (const float*)d_in[11];
  const float* xmb  = (const float*)d_in[12];
  const float* xlw  = (const float*)d_in[13];
  const float* xlb  = (const float*)d_in[14];
  const float* pxw0 = (const float*)d_in[15];
  const float* pxb0 = (const float*)d_in[16];
  const float* pxw1 = (const float*)d_in[17];
  const float* pxb1 = (const float*)d_in[18];
  const float* mw0  = (const float*)d_in[19];
  const float* mb0  = (const float*)d_in[20];
  const float* mw1  = (const float*)d_in[21];
  const float* mb1  = (const float*)d_in[22];
  const float* gwih = (const float*)d_in[23];
  const float* gwhh = (const float*)d_in[24];
  const float* Cw   = (const float*)d_in[25];

  char* w = (char*)d_ws;
  u16* hst = (u16*)w; w += (size_t)2 * 1024 * 128 * 2;
  size_t used_head = (size_t)2 * 1024 * 128 * 2 + 4096;
  size_t avail = (ws_size > used_head) ? (ws_size - used_head) : 0;
  int Tc = 1024;
  while (Tc > 32 && (size_t)1024 * (size_t)Tc * (128 + 384 + 128 + 32) * 2 > avail) Tc >>= 1;
  u16* phi  = (u16*)w; w += (size_t)1024 * Tc * 128 * 2;
  u16* gi0  = (u16*)w; w += (size_t)1024 * Tc * 384 * 2;
  u16* Hs   = (u16*)w; w += (size_t)1024 * Tc * 128 * 2;
  u16* xmlv = (u16*)w; w += (size_t)1024 * Tc * 32 * 2;

  hipMemsetAsync(d_out, 0, sizeof(float), stream);
  k_inith<<<1024, 256, 0, stream>>>(h0, hst);
  for (int t0 = 0; t0 < 1024; t0 += Tc){
    k_phiu<<<1024, 512, 0, stream>>>(u, puw0, pub0, puw1, pub1, phi, t0, Tc);
    k_gi0<<<256, 512, 0, stream>>>(phi, gwih, gi0, Tc);
    k_gru<<<64, 512, 0, stream>>>(gi0, gwhh, gwih, hst, Hs, Tc);
    k_c1<<<256, 512, 0, stream>>>(phi, Hs, dw0, db0, dw1, db1, xmw, xmb, xlw, xlb, xmlv, Tc);
    k_c2<<<256, 512, 0, stream>>>(xmlv, y, pxw0, pxb0, pxw1, pxb1, mw0, mb0, mw1, mb1, Cw,
                                  (float*)d_out, t0, Tc);
  }
}

// Round 2
// 3921.273 us; speedup vs baseline: 2.0029x; 2.0029x over previous
//
#include <hip/hip_runtime.h>
#include <hip/hip_bf16.h>

typedef unsigned short u16;
using short8 = __attribute__((ext_vector_type(8))) short;
using f32x4  = __attribute__((ext_vector_type(4))) float;

#define DEVINL static __device__ __forceinline__

DEVINL float bf2f(u16 u){
  union { unsigned int i; float f; } x; x.i = ((unsigned int)u) << 16; return x.f;
}
DEVINL u16 f2bf(float f){
  union { float f; unsigned int i; } x; x.f = f;
  unsigned int i = x.i;
  return (u16)((i + 0x7FFFu + ((i >> 16) & 1u)) >> 16);
}
DEVINL float sigm(float x){ return 1.f / (1.f + __expf(-x)); }
DEVINL float tanhf_(float x){
  x = fminf(fmaxf(x, -20.f), 20.f);
  float e = __expf(-2.f * x);
  return (1.f - e) / (1.f + e);
}
DEVINL f32x4 zero4(){ f32x4 z = {0.f, 0.f, 0.f, 0.f}; return z; }

DEVINL f32x4 mfma16(short8 a, short8 b, f32x4 c){
  return __builtin_amdgcn_mfma_f32_16x16x32_bf16(a, b, c, 0, 0, 0);
}

// lane l: row = l&15, k0 = (l>>4)*8 ; 16B vector read. stride in u16 elements (must keep rows 16B aligned)
DEVINL short8 frag_ld(const u16* base, int stride){
  int l = threadIdx.x & 63;
  return *(const short8*)(base + (l & 15) * stride + ((l >> 4) << 3));
}
// fragment load directly from global, row stride in u16, ks selects 32-col K slice
DEVINL short8 gfrag(const u16* rowbase, int stride, int ks){
  int l = threadIdx.x & 63;
  return *(const short8*)(rowbase + (size_t)(l & 15) * stride + ks * 32 + ((l >> 4) << 3));
}

// acc layout: col = lane&15 (+col_base), rows = (lane>>4)*4 + r
DEVINL void acc_store_lds(u16* dst, int stride, int col_base, f32x4 acc, float bias, bool relu){
  int l = threadIdx.x & 63;
  int col = col_base + (l & 15);
  int row0 = (l >> 4) * 4;
  #pragma unroll
  for (int r = 0; r < 4; r++){
    float v = acc[r] + bias;
    if (relu) v = fmaxf(v, 0.f);
    dst[(row0 + r) * stride + col] = f2bf(v);
  }
}

// stage fp32 (N,K) row-major weights -> bf16 LDS [N][Kp+8]; zero cols K..Kp
DEVINL void stage_weights(u16* dst, const float* src, int N, int K, int Kp){
  int stride = Kp + 8;
  if (Kp > K){
    int padw = Kp - K;
    for (int i = threadIdx.x; i < N * padw; i += blockDim.x){
      int n = i / padw, k = K + (i - (i / padw) * padw);
      dst[n * stride + k] = 0;
    }
  }
  for (int i = threadIdx.x * 4; i < N * K; i += blockDim.x * 4){
    float4 v = *(const float4*)(src + i);
    int n = i / K, k = i - n * K;
    u16* d = dst + n * stride + k;
    d[0] = f2bf(v.x); d[1] = f2bf(v.y); d[2] = f2bf(v.z); d[3] = f2bf(v.w);
  }
}

__global__ __launch_bounds__(256) void k_inith(const float* __restrict__ h0, u16* __restrict__ hst){
  int i = blockIdx.x * 256 + threadIdx.x;
  if (i < 2 * 1024 * 128) hst[i] = f2bf(h0[i]);
}

// ---------------- phase A: phi_u, per-wave independent tiles, no inner barriers ----------------
__global__ __launch_bounds__(512, 4) void k_phiu(const float* __restrict__ u,
    const float* __restrict__ w0, const float* __restrict__ b0,
    const float* __restrict__ w1, const float* __restrict__ b1,
    u16* __restrict__ phi, int t0, int Tc){
  __shared__ __align__(16) u16 w0s[128 * 40];
  __shared__ __align__(16) u16 w1s[128 * 136];
  __shared__ __align__(16) u16 buf[8][16 * 136];
  stage_weights(w0s, w0, 128, 16, 32);
  stage_weights(w1s, w1, 128, 128, 128);
  int wv = threadIdx.x >> 6, l = threadIdx.x & 63;
  u16* mybuf = buf[wv];
  float b0v[8], b1v[8];
  #pragma unroll
  for (int nt = 0; nt < 8; nt++){
    b0v[nt] = b0[nt * 16 + (l & 15)];
    b1v[nt] = b1[nt * 16 + (l & 15)];
  }
  __syncthreads();
  int tpb = Tc >> 4;
  int ntile = 1024 * tpb;
  int stride = gridDim.x * 8;
  for (int tile = blockIdx.x * 8 + wv; tile < ntile; tile += stride){
    int b = tile / tpb;
    int tt = (tile - b * tpb) << 4;
    // stage 16x16 u tile transposed into mybuf rows t, cols k ; zero-pad cols 16..31
    int t = l & 15, kb = l >> 4;
    #pragma unroll
    for (int j = 0; j < 4; j++){
      int k = kb + j * 4;
      mybuf[t * 136 + k] = f2bf(u[(size_t)(b * 16 + k) * 1024 + t0 + tt + t]);
      mybuf[t * 136 + 16 + k] = 0;
    }
    short8 a0 = frag_ld(mybuf, 136);
    f32x4 acc[8];
    #pragma unroll
    for (int nt = 0; nt < 8; nt++)
      acc[nt] = mfma16(a0, frag_ld(w0s + nt * 16 * 40, 40), zero4());
    #pragma unroll
    for (int nt = 0; nt < 8; nt++)
      acc_store_lds(mybuf, 136, nt * 16, acc[nt], b0v[nt], true);
    f32x4 a2[8];
    #pragma unroll
    for (int nt = 0; nt < 8; nt++) a2[nt] = zero4();
    #pragma unroll
    for (int ks = 0; ks < 4; ks++){
      short8 a = frag_ld(mybuf + ks * 32, 136);
      #pragma unroll
      for (int nt = 0; nt < 8; nt++)
        a2[nt] = mfma16(a, frag_ld(w1s + nt * 16 * 136 + ks * 32, 136), a2[nt]);
    }
    #pragma unroll
    for (int nt = 0; nt < 8; nt++)
      acc_store_lds(mybuf, 136, nt * 16, a2[nt], b1v[nt], false);
    // vectorized copy mybuf -> phi (16 rows x 128)
    u16* dst = phi + (size_t)(b * Tc + tt) * 128;
    #pragma unroll
    for (int j = 0; j < 4; j++){
      int c = j * 64 + l;
      int row = c >> 4, k = (c & 15) * 8;
      *(short8*)(dst + row * 128 + k) = *(const short8*)(mybuf + row * 136 + k);
    }
  }
}

DEVINL void stage_phi(u16* dst, const u16* __restrict__ phi, int b0, int Tc, int t){
  int i = threadIdx.x;           // 512 threads x 8B = 4KB
  int row = i >> 5, k = (i & 31) * 4;
  *(uint2*)(dst + row * 136 + k) =
      *(const uint2*)(phi + ((size_t)(b0 + row) * Tc + t) * 128 + k);
}

// ---------------- phase B: sequential 2-layer GRU + fused gi0 ----------------
__global__ __launch_bounds__(512, 2) void k_gru(const u16* __restrict__ phi,
    const float* __restrict__ gwih, const float* __restrict__ gwhh,
    u16* __restrict__ hst, u16* __restrict__ Hs, int Tc){
  __shared__ __align__(16) u16 wi0[384 * 136];
  __shared__ __align__(16) u16 h0s[2][16 * 136];
  __shared__ __align__(16) u16 h1s[16 * 136];
  __shared__ __align__(16) u16 pb[2][16 * 136];
  stage_weights(wi0, gwih, 384, 128, 128);   // layer0 W_ih in LDS
  int wv = threadIdx.x >> 6, l = threadIdx.x & 63;
  int b0 = blockIdx.x * 16;
  int m0 = (l >> 4) * 4;
  int colw = wv * 16 + (l & 15);
  // stationary register weights: whh0, wih1, whh1
  const float* srcs[3] = { gwhh, gwih + 384 * 128, gwhh + 384 * 128 };
  short8 wB[3][3][4];
  #pragma unroll
  for (int mm = 0; mm < 3; mm++){
    #pragma unroll
    for (int g = 0; g < 3; g++){
      int n = g * 128 + wv * 16 + (l & 15);
      #pragma unroll
      for (int ks = 0; ks < 4; ks++){
        const float* p = srcs[mm] + (size_t)n * 128 + ks * 32 + ((l >> 4) << 3);
        float4 va = *(const float4*)p;
        float4 vb = *(const float4*)(p + 4);
        short8 f;
        f[0] = (short)f2bf(va.x); f[1] = (short)f2bf(va.y);
        f[2] = (short)f2bf(va.z); f[3] = (short)f2bf(va.w);
        f[4] = (short)f2bf(vb.x); f[5] = (short)f2bf(vb.y);
        f[6] = (short)f2bf(vb.z); f[7] = (short)f2bf(vb.w);
        wB[mm][g][ks] = f;
      }
    }
  }
  // restore state
  for (int i = threadIdx.x * 4; i < 4096; i += 2048){
    int layer = i >> 11, j = i & 2047;
    int row = j >> 7, k = j & 127;
    u16* d = (layer ? h1s : h0s[0]) + row * 136 + k;
    *(uint2*)d = *(const uint2*)(hst + layer * 131072 + (b0 + row) * 128 + k);
  }
  __syncthreads();
  float h0reg[4], h1reg[4];
  #pragma unroll
  for (int r = 0; r < 4; r++){
    h0reg[r] = bf2f(h0s[0][(m0 + r) * 136 + colw]);
    h1reg[r] = bf2f(h1s[(m0 + r) * 136 + colw]);
  }
  // prologue: pb0 <- phi(0); gcur = gi(0); pb1 <- phi(1)
  stage_phi(pb[0], phi, b0, Tc, 0);
  __syncthreads();
  float gcur[3][4];
  {
    short8 a[4];
    #pragma unroll
    for (int ks = 0; ks < 4; ks++) a[ks] = frag_ld(pb[0] + ks * 32, 136);
    #pragma unroll
    for (int g = 0; g < 3; g++){
      f32x4 acc = zero4();
      #pragma unroll
      for (int ks = 0; ks < 4; ks++)
        acc = mfma16(a[ks], frag_ld(wi0 + (g * 128 + wv * 16) * 136 + ks * 32, 136), acc);
      #pragma unroll
      for (int r = 0; r < 4; r++) gcur[g][r] = acc[r];
    }
  }
  if (Tc > 1) stage_phi(pb[1], phi, b0, Tc, 1);
  __syncthreads();

  int p = 0;
  for (int t = 0; t < Tc; t++){
    // Hs(t) <- h1s (h1 before step t), coalesced 4KB block copy
    {
      int c = threadIdx.x;
      int row = c >> 5, k = (c & 31) * 4;
      *(uint2*)(Hs + ((size_t)(b0 + row) * Tc + t) * 128 + k) =
          *(const uint2*)(h1s + row * 136 + k);
    }
    // [1] stage phi(t+2) into pb[p] (its last readers were 2 steps ago)
    if (t + 2 < Tc) stage_phi(pb[p], phi, b0, Tc, t + 2);
    // [2a] gnxt = gi(t+1) from pb[p^1] (staged last step, barrier since)
    float gnxt[3][4];
    if (t + 1 < Tc){
      short8 a[4];
      #pragma unroll
      for (int ks = 0; ks < 4; ks++) a[ks] = frag_ld(pb[p ^ 1] + ks * 32, 136);
      #pragma unroll
      for (int g = 0; g < 3; g++){
        f32x4 acc = zero4();
        #pragma unroll
        for (int ks = 0; ks < 4; ks++)
          acc = mfma16(a[ks], frag_ld(wi0 + (g * 128 + wv * 16) * 136 + ks * 32, 136), acc);
        #pragma unroll
        for (int r = 0; r < 4; r++) gnxt[g][r] = acc[r];
      }
    } else {
      #pragma unroll
      for (int g = 0; g < 3; g++)
        #pragma unroll
        for (int r = 0; r < 4; r++) gnxt[g][r] = 0.f;
    }
    // [2b] gh0 (from h0s[p]) and gh1 (from h1s)
    short8 a[4];
    f32x4 gh0[3], gh1[3];
    #pragma unroll
    for (int g = 0; g < 3; g++){ gh0[g] = zero4(); gh1[g] = zero4(); }
    #pragma unroll
    for (int ks = 0; ks < 4; ks++) a[ks] = frag_ld(h0s[p] + ks * 32, 136);
    #pragma unroll
    for (int g = 0; g < 3; g++)
      #pragma unroll
      for (int ks = 0; ks < 4; ks++)
        gh0[g] = mfma16(a[ks], wB[0][g][ks], gh0[g]);
    #pragma unroll
    for (int ks = 0; ks < 4; ks++) a[ks] = frag_ld(h1s + ks * 32, 136);
    #pragma unroll
    for (int g = 0; g < 3; g++)
      #pragma unroll
      for (int ks = 0; ks < 4; ks++)
        gh1[g] = mfma16(a[ks], wB[2][g][ks], gh1[g]);
    // layer-0 gates
    #pragma unroll
    for (int r = 0; r < 4; r++){
      float rg = sigm(gcur[0][r] + gh0[0][r]);
      float zg = sigm(gcur[1][r] + gh0[1][r]);
      float ng = tanhf_(gcur[2][r] + rg * gh0[2][r]);
      float hn = (1.f - zg) * ng + zg * h0reg[r];
      h0reg[r] = hn;
      h0s[p ^ 1][(m0 + r) * 136 + colw] = f2bf(hn);
    }
    __syncthreads();   // barrier A: new h0 visible; all h1s reads done
    // gi1 = h0_new @ wih1^T
    f32x4 gi1[3];
    #pragma unroll
    for (int g = 0; g < 3; g++) gi1[g] = zero4();
    #pragma unroll
    for (int ks = 0; ks < 4; ks++) a[ks] = frag_ld(h0s[p ^ 1] + ks * 32, 136);
    #pragma unroll
    for (int g = 0; g < 3; g++)
      #pragma unroll
      for (int ks = 0; ks < 4; ks++)
        gi1[g] = mfma16(a[ks], wB[1][g][ks], gi1[g]);
    // layer-1 gates
    #pragma unroll
    for (int r = 0; r < 4; r++){
      float rg = sigm(gi1[0][r] + gh1[0][r]);
      float zg = sigm(gi1[1][r] + gh1[1][r]);
      float ng = tanhf_(gi1[2][r] + rg * gh1[2][r]);
      float hn = (1.f - zg) * ng + zg * h1reg[r];
      h1reg[r] = hn;
      h1s[(m0 + r) * 136 + colw] = f2bf(hn);
    }
    #pragma unroll
    for (int g = 0; g < 3; g++)
      #pragma unroll
      for (int r = 0; r < 4; r++) gcur[g][r] = gnxt[g][r];
    p ^= 1;
    __syncthreads();   // barrier B: new h1 + staged pb visible
  }
  // save state
  for (int i = threadIdx.x * 4; i < 4096; i += 2048){
    int layer = i >> 11, j = i & 2047;
    int row = j >> 7, k = j & 127;
    const u16* s = (layer ? h1s : h0s[p]) + row * 136 + k;
    *(uint2*)(hst + layer * 131072 + (b0 + row) * 128 + k) = *(const uint2*)s;
  }
}

// ---------------- phase C1: dynn + x_mean/x_logvar, per-wave tiles ----------------
__global__ __launch_bounds__(512, 2) void k_c1(const u16* __restrict__ phi, const u16* __restrict__ Hs,
    const float* __restrict__ dw0, const float* __restrict__ db0,
    const float* __restrict__ dw1, const float* __restrict__ db1,
    const float* __restrict__ xmw, const float* __restrict__ xmb,
    const float* __restrict__ xlw, const float* __restrict__ xlb,
    u16* __restrict__ xmlv, int Tc){
  __shared__ __align__(16) u16 w0s[128 * 264];
  __shared__ __align__(16) u16 w1s[128 * 136];
  __shared__ __align__(16) u16 xws[32 * 136];
  __shared__ __align__(16) u16 buf[8][16 * 136];
  stage_weights(w0s, dw0, 128, 256, 256);
  stage_weights(w1s, dw1, 128, 128, 128);
  stage_weights(xws, xmw, 16, 128, 128);
  stage_weights(xws + 16 * 136, xlw, 16, 128, 128);
  int wv = threadIdx.x >> 6, l = threadIdx.x & 63;
  u16* mybuf = buf[wv];
  float b0v[8], b1v[8];
  #pragma unroll
  for (int nt = 0; nt < 8; nt++){
    b0v[nt] = db0[nt * 16 + (l & 15)];
    b1v[nt] = db1[nt * 16 + (l & 15)];
  }
  float bxm = xmb[l & 15], bxl = xlb[l & 15];
  __syncthreads();
  int tpb = Tc >> 4;
  int ntile = 1024 * tpb;
  int stride = gridDim.x * 8;
  for (int tile = blockIdx.x * 8 + wv; tile < ntile; tile += stride){
    int b = tile / tpb;
    int tt = (tile - b * tpb) << 4;
    size_t rbase = (size_t)(b * Tc + tt);
    const u16* ap = phi + rbase * 128;
    const u16* hp = Hs + rbase * 128;
    f32x4 acc[8];
    #pragma unroll
    for (int nt = 0; nt < 8; nt++) acc[nt] = zero4();
    #pragma unroll
    for (int ks = 0; ks < 8; ks++){
      short8 a = (ks < 4) ? gfrag(ap, 128, ks) : gfrag(hp, 128, ks - 4);
      #pragma unroll
      for (int nt = 0; nt < 8; nt++)
        acc[nt] = mfma16(a, frag_ld(w0s + nt * 16 * 264 + ks * 32, 264), acc[nt]);
    }
    #pragma unroll
    for (int nt = 0; nt < 8; nt++)
      acc_store_lds(mybuf, 136, nt * 16, acc[nt], b0v[nt], true);
    f32x4 a2[8];
    #pragma unroll
    for (int nt = 0; nt < 8; nt++) a2[nt] = zero4();
    #pragma unroll
    for (int ks = 0; ks < 4; ks++){
      short8 a = frag_ld(mybuf + ks * 32, 136);
      #pragma unroll
      for (int nt = 0; nt < 8; nt++)
        a2[nt] = mfma16(a, frag_ld(w1s + nt * 16 * 136 + ks * 32, 136), a2[nt]);
    }
    #pragma unroll
    for (int nt = 0; nt < 8; nt++)
      acc_store_lds(mybuf, 136, nt * 16, a2[nt], b1v[nt], false);
    f32x4 am = zero4(), al = zero4();
    #pragma unroll
    for (int ks = 0; ks < 4; ks++){
      short8 a = frag_ld(mybuf + ks * 32, 136);
      am = mfma16(a, frag_ld(xws + ks * 32, 136), am);
      al = mfma16(a, frag_ld(xws + 16 * 136 + ks * 32, 136), al);
    }
    acc_store_lds(mybuf, 136, 0, am, bxm, false);
    acc_store_lds(mybuf, 136, 16, al, bxl, false);
    // vectorized copy 16x32 -> xmlv
    u16* dst = xmlv + rbase * 32;
    int c = l;
    int row = c >> 2, k = (c & 3) * 8;
    *(short8*)(dst + row * 32 + k) = *(const short8*)(mybuf + row * 136 + k);
  }
}

// ---------------- phase C2: phi_x + menn + C@x_mean + loss, per-wave tiles ----------------
__global__ __launch_bounds__(512, 2) void k_c2(const u16* __restrict__ xmlv, const float* __restrict__ y,
    const float* __restrict__ pw0, const float* __restrict__ pb0,
    const float* __restrict__ pw1, const float* __restrict__ pb1,
    const float* __restrict__ mw0, const float* __restrict__ mb0,
    const float* __restrict__ mw1, const float* __restrict__ mb1,
    const float* __restrict__ Cw, float* __restrict__ out, int t0, int Tc){
  __shared__ __align__(16) u16 pw0s[128 * 40];
  __shared__ __align__(16) u16 pw1s[128 * 136];
  __shared__ __align__(16) u16 mw0s[128 * 136];
  __shared__ __align__(16) u16 mw1s[16 * 136];
  __shared__ __align__(16) u16 Cs[16 * 40];
  __shared__ __align__(16) u16 buf[8][16 * 136];
  stage_weights(pw0s, pw0, 128, 32, 32);
  stage_weights(pw1s, pw1, 128, 128, 128);
  stage_weights(mw0s, mw0, 128, 128, 128);
  stage_weights(mw1s, mw1, 16, 128, 128);
  stage_weights(Cs, Cw, 16, 16, 32);
  int wv = threadIdx.x >> 6, l = threadIdx.x & 63;
  u16* mybuf = buf[wv];
  float bp0v[8], bp1v[8], bm0v[8];
  #pragma unroll
  for (int nt = 0; nt < 8; nt++){
    bp0v[nt] = pb0[nt * 16 + (l & 15)];
    bp1v[nt] = pb1[nt * 16 + (l & 15)];
    bm0v[nt] = mb0[nt * 16 + (l & 15)];
  }
  float bm1 = mb1[l & 15];
  __syncthreads();
  float lacc = 0.f;
  int tpb = Tc >> 4;
  int ntile = 1024 * tpb;
  int stride = gridDim.x * 8;
  for (int tile = blockIdx.x * 8 + wv; tile < ntile; tile += stride){
    int b = tile / tpb;
    int tt = (tile - b * tpb) << 4;
    size_t rbase = (size_t)(b * Tc + tt);
    const u16* xp = xmlv + rbase * 32;
    short8 a0 = gfrag(xp, 32, 0);
    f32x4 acc[8];
    #pragma unroll
    for (int nt = 0; nt < 8; nt++)
      acc[nt] = mfma16(a0, frag_ld(pw0s + nt * 16 * 40, 40), zero4());
    #pragma unroll
    for (int nt = 0; nt < 8; nt++)
      acc_store_lds(mybuf, 136, nt * 16, acc[nt], bp0v[nt], true);
    f32x4 a2[8];
    #pragma unroll
    for (int nt = 0; nt < 8; nt++) a2[nt] = zero4();
    #pragma unroll
    for (int ks = 0; ks < 4; ks++){
      short8 a = frag_ld(mybuf + ks * 32, 136);
      #pragma unroll
      for (int nt = 0; nt < 8; nt++)
        a2[nt] = mfma16(a, frag_ld(pw1s + nt * 16 * 136 + ks * 32, 136), a2[nt]);
    }
    #pragma unroll
    for (int nt = 0; nt < 8; nt++)
      acc_store_lds(mybuf, 136, nt * 16, a2[nt], bp1v[nt], false);
    f32x4 a3[8];
    #pragma unroll
    for (int nt = 0; nt < 8; nt++) a3[nt] = zero4();
    #pragma unroll
    for (int ks = 0; ks < 4; ks++){
      short8 a = frag_ld(mybuf + ks * 32, 136);
      #pragma unroll
      for (int nt = 0; nt < 8; nt++)
        a3[nt] = mfma16(a, frag_ld(mw0s + nt * 16 * 136 + ks * 32, 136), a3[nt]);
    }
    #pragma unroll
    for (int nt = 0; nt < 8; nt++)
      acc_store_lds(mybuf, 136, nt * 16, a3[nt], bm0v[nt], true);
    f32x4 ay = zero4();
    #pragma unroll
    for (int ks = 0; ks < 4; ks++){
      short8 a = frag_ld(mybuf + ks * 32, 136);
      ay = mfma16(a, frag_ld(mw1s + ks * 32, 136), ay);
    }
    f32x4 ac = mfma16(a0, frag_ld(Cs, 40), zero4());  // cols>=16 zero-padded: only x_mean contributes
    #pragma unroll
    for (int r = 0; r < 4; r++){
      float yh = ay[r] + bm1 + ac[r];
      int m = (l >> 4) * 4 + r, j = l & 15;
      float d = yh - y[(size_t)(b * 16 + j) * 1024 + t0 + tt + m];
      lacc += d * d;
    }
  }
  #pragma unroll
  for (int off = 32; off > 0; off >>= 1)
    lacc += __shfl_down(lacc, off);
  if (l == 0) atomicAdd(out, lacc);
}

extern "C" void kernel_launch(void* const* d_in, const int* in_sizes, int n_in,
                              void* d_out, int out_size, void* d_ws, size_t ws_size,
                              hipStream_t stream){
  const float* u    = (const float*)d_in[0];
  const float* y    = (const float*)d_in[1];
  const float* h0   = (const float*)d_in[2];
  const float* puw0 = (const float*)d_in[3];
  const float* pub0 = (const float*)d_in[4];
  const float* puw1 = (const float*)d_in[5];
  const float* pub1 = (const float*)d_in[6];
  const float* dw0  = (const float*)d_in[7];
  const float* db0  = (const float*)d_in[8];
  const float* dw1  = (const float*)d_in[9];
  const float* db1  = (const float*)d_in[10];
  const float* xmw  = (const float*)d_in[11];
  const float* xmb  = (const float*)d_in[12];
  const float* xlw  = (const float*)d_in[13];
  const float* xlb  = (const float*)d_in[14];
  const float* pxw0 = (const float*)d_in[15];
  const float* pxb0 = (const float*)d_in[16];
  const float* pxw1 = (const float*)d_in[17];
  const float* pxb1 = (const float*)d_in[18];
  const float* mw0  = (const float*)d_in[19];
  const float* mb0  = (const float*)d_in[20];
  const float* mw1  = (const float*)d_in[21];
  const float* mb1  = (const float*)d_in[22];
  const float* gwih = (const float*)d_in[23];
  const float* gwhh = (const float*)d_in[24];
  const float* Cw   = (const float*)d_in[25];

  char* w = (char*)d_ws;
  u16* hst = (u16*)w; w += (size_t)2 * 1024 * 128 * 2;
  size_t head = (size_t)2 * 1024 * 128 * 2 + 4096;
  size_t avail = (ws_size > head) ? (ws_size - head) : 0;
  int Tc = 1024;
  while (Tc > 64 && (size_t)1024 * (size_t)Tc * (128 + 128 + 32) * 2 > avail) Tc >>= 1;
  u16* phi  = (u16*)w; w += (size_t)1024 * Tc * 128 * 2;
  u16* Hs   = (u16*)w; w += (size_t)1024 * Tc * 128 * 2;
  u16* xmlv = (u16*)w; w += (size_t)1024 * Tc * 32 * 2;

  hipMemsetAsync(d_out, 0, sizeof(float), stream);
  k_inith<<<1024, 256, 0, stream>>>(h0, hst);
  for (int t0 = 0; t0 < 1024; t0 += Tc){
    k_phiu<<<512, 512, 0, stream>>>(u, puw0, pub0, puw1, pub1, phi, t0, Tc);
    k_gru<<<64, 512, 0, stream>>>(phi, gwih, gwhh, hst, Hs, Tc);
    k_c1<<<256, 512, 0, stream>>>(phi, Hs, dw0, db0, dw1, db1, xmw, xmb, xlw, xlb, xmlv, Tc);
    k_c2<<<256, 512, 0, stream>>>(xmlv, y, pxw0, pxb0, pxw1, pxb1, mw0, mb0, mw1, mb1, Cw,
                                  (float*)d_out, t0, Tc);
  }
}

// Round 3
// 3570.551 us; speedup vs baseline: 2.1997x; 1.0982x over previous
//
#include <hip/hip_runtime.h>
#include <hip/hip_bf16.h>

typedef unsigned short u16;
using short8 = __attribute__((ext_vector_type(8))) short;
using f32x4  = __attribute__((ext_vector_type(4))) float;

#define DEVINL static __device__ __forceinline__

DEVINL float bf2f(u16 u){
  union { unsigned int i; float f; } x; x.i = ((unsigned int)u) << 16; return x.f;
}
DEVINL u16 f2bf(float f){
  union { float f; unsigned int i; } x; x.f = f;
  unsigned int i = x.i;
  return (u16)((i + 0x7FFFu + ((i >> 16) & 1u)) >> 16);
}
DEVINL float sigm(float x){ return 1.f / (1.f + __expf(-x)); }
DEVINL float tanhf_(float x){
  x = fminf(fmaxf(x, -20.f), 20.f);
  float e = __expf(-2.f * x);
  return (1.f - e) / (1.f + e);
}
DEVINL f32x4 zero4(){ f32x4 z = {0.f, 0.f, 0.f, 0.f}; return z; }

DEVINL f32x4 mfma16(short8 a, short8 b, f32x4 c){
  return __builtin_amdgcn_mfma_f32_16x16x32_bf16(a, b, c, 0, 0, 0);
}

// lane l: row = l&15, k0 = (l>>4)*8 ; 16B vector read. stride in u16 elements (rows 16B-aligned)
DEVINL short8 frag_ld(const u16* base, int stride){
  int l = threadIdx.x & 63;
  return *(const short8*)(base + (l & 15) * stride + ((l >> 4) << 3));
}
// fragment load directly from global, row stride in u16, ks selects 32-col K slice
DEVINL short8 gfrag(const u16* rowbase, int stride, int ks){
  int l = threadIdx.x & 63;
  return *(const short8*)(rowbase + (size_t)(l & 15) * stride + ks * 32 + ((l >> 4) << 3));
}

// acc layout: col = lane&15 (+col_base), rows = (lane>>4)*4 + r
DEVINL void acc_store_lds(u16* dst, int stride, int col_base, f32x4 acc, float bias, bool relu){
  int l = threadIdx.x & 63;
  int col = col_base + (l & 15);
  int row0 = (l >> 4) * 4;
  #pragma unroll
  for (int r = 0; r < 4; r++){
    float v = acc[r] + bias;
    if (relu) v = fmaxf(v, 0.f);
    dst[(row0 + r) * stride + col] = f2bf(v);
  }
}

// stage fp32 (N,K) row-major weights -> bf16 LDS [N][Kp+8]; zero cols K..Kp
DEVINL void stage_weights(u16* dst, const float* src, int N, int K, int Kp){
  int stride = Kp + 8;
  if (Kp > K){
    int padw = Kp - K;
    for (int i = threadIdx.x; i < N * padw; i += blockDim.x){
      int n = i / padw, k = K + (i - (i / padw) * padw);
      dst[n * stride + k] = 0;
    }
  }
  for (int i = threadIdx.x * 4; i < N * K; i += blockDim.x * 4){
    float4 v = *(const float4*)(src + i);
    int n = i / K, k = i - n * K;
    u16* d = dst + n * stride + k;
    d[0] = f2bf(v.x); d[1] = f2bf(v.y); d[2] = f2bf(v.z); d[3] = f2bf(v.w);
  }
}

__global__ __launch_bounds__(256) void k_inith(const float* __restrict__ h0, u16* __restrict__ hst){
  int i = blockIdx.x * 256 + threadIdx.x;
  if (i < 2 * 1024 * 128) hst[i] = f2bf(h0[i]);
}

// ---------------- phase A: phi_u, per-wave independent tiles, no inner barriers ----------------
__global__ __launch_bounds__(512, 4) void k_phiu(const float* __restrict__ u,
    const float* __restrict__ w0, const float* __restrict__ b0,
    const float* __restrict__ w1, const float* __restrict__ b1,
    u16* __restrict__ phi, int t0, int Tc){
  __shared__ __align__(16) u16 w0s[128 * 40];
  __shared__ __align__(16) u16 w1s[128 * 136];
  __shared__ __align__(16) u16 buf[8][16 * 136];
  stage_weights(w0s, w0, 128, 16, 32);
  stage_weights(w1s, w1, 128, 128, 128);
  int wv = threadIdx.x >> 6, l = threadIdx.x & 63;
  u16* mybuf = buf[wv];
  float b0v[8], b1v[8];
  #pragma unroll
  for (int nt = 0; nt < 8; nt++){
    b0v[nt] = b0[nt * 16 + (l & 15)];
    b1v[nt] = b1[nt * 16 + (l & 15)];
  }
  __syncthreads();
  int tpb = Tc >> 4;
  int ntile = 1024 * tpb;
  int stride = gridDim.x * 8;
  for (int tile = blockIdx.x * 8 + wv; tile < ntile; tile += stride){
    int b = tile / tpb;
    int tt = (tile - b * tpb) << 4;
    int t = l & 15, kb = l >> 4;
    #pragma unroll
    for (int j = 0; j < 4; j++){
      int k = kb + j * 4;
      mybuf[t * 136 + k] = f2bf(u[(size_t)(b * 16 + k) * 1024 + t0 + tt + t]);
      mybuf[t * 136 + 16 + k] = 0;
    }
    short8 a0 = frag_ld(mybuf, 136);
    f32x4 acc[8];
    #pragma unroll
    for (int nt = 0; nt < 8; nt++)
      acc[nt] = mfma16(a0, frag_ld(w0s + nt * 16 * 40, 40), zero4());
    #pragma unroll
    for (int nt = 0; nt < 8; nt++)
      acc_store_lds(mybuf, 136, nt * 16, acc[nt], b0v[nt], true);
    f32x4 a2[8];
    #pragma unroll
    for (int nt = 0; nt < 8; nt++) a2[nt] = zero4();
    #pragma unroll
    for (int ks = 0; ks < 4; ks++){
      short8 a = frag_ld(mybuf + ks * 32, 136);
      #pragma unroll
      for (int nt = 0; nt < 8; nt++)
        a2[nt] = mfma16(a, frag_ld(w1s + nt * 16 * 136 + ks * 32, 136), a2[nt]);
    }
    #pragma unroll
    for (int nt = 0; nt < 8; nt++)
      acc_store_lds(mybuf, 136, nt * 16, a2[nt], b1v[nt], false);
    u16* dst = phi + (size_t)(b * Tc + tt) * 128;
    #pragma unroll
    for (int j = 0; j < 4; j++){
      int c = j * 64 + l;
      int row = c >> 4, k = (c & 15) * 8;
      *(short8*)(dst + row * 128 + k) = *(const short8*)(mybuf + row * 136 + k);
    }
  }
}

// 512 threads x 8B = one 16x128 bf16 tile
DEVINL uint2 phi_ldreg(const u16* __restrict__ phi, int b0, int Tc, int t){
  int i = threadIdx.x;
  int row = i >> 5, k = (i & 31) * 4;
  return *(const uint2*)(phi + ((size_t)(b0 + row) * Tc + t) * 128 + k);
}
DEVINL void pb_write(u16* dst, uint2 v){
  int i = threadIdx.x;
  int row = i >> 5, k = (i & 31) * 4;
  *(uint2*)(dst + row * 136 + k) = v;
}

// ---------------- phase B: sequential 2-layer GRU + fused gi0, raw-barrier loop ----------------
__global__ __launch_bounds__(512, 2) void k_gru(const u16* __restrict__ phi,
    const float* __restrict__ gwih, const float* __restrict__ gwhh,
    u16* __restrict__ hst, u16* __restrict__ Hs, int Tc){
  __shared__ __align__(16) u16 wi0[384 * 136];
  __shared__ __align__(16) u16 h0s[2][16 * 136];
  __shared__ __align__(16) u16 h1s[16 * 136];
  __shared__ __align__(16) u16 pb[2][16 * 136];
  stage_weights(wi0, gwih, 384, 128, 128);   // layer0 W_ih in LDS
  int wv = threadIdx.x >> 6, l = threadIdx.x & 63;
  int b0 = blockIdx.x * 16;
  int m0 = (l >> 4) * 4;
  int colw = wv * 16 + (l & 15);
  // stationary register (AGPR) weights: whh0, wih1, whh1
  const float* srcs[3] = { gwhh, gwih + 384 * 128, gwhh + 384 * 128 };
  short8 wB[3][3][4];
  #pragma unroll
  for (int mm = 0; mm < 3; mm++){
    #pragma unroll
    for (int g = 0; g < 3; g++){
      int n = g * 128 + wv * 16 + (l & 15);
      #pragma unroll
      for (int ks = 0; ks < 4; ks++){
        const float* p = srcs[mm] + (size_t)n * 128 + ks * 32 + ((l >> 4) << 3);
        float4 va = *(const float4*)p;
        float4 vb = *(const float4*)(p + 4);
        short8 f;
        f[0] = (short)f2bf(va.x); f[1] = (short)f2bf(va.y);
        f[2] = (short)f2bf(va.z); f[3] = (short)f2bf(va.w);
        f[4] = (short)f2bf(vb.x); f[5] = (short)f2bf(vb.y);
        f[6] = (short)f2bf(vb.z); f[7] = (short)f2bf(vb.w);
        wB[mm][g][ks] = f;
      }
    }
  }
  // restore state
  for (int i = threadIdx.x * 4; i < 4096; i += 2048){
    int layer = i >> 11, j = i & 2047;
    int row = j >> 7, k = j & 127;
    u16* d = (layer ? h1s : h0s[0]) + row * 136 + k;
    *(uint2*)d = *(const uint2*)(hst + layer * 131072 + (b0 + row) * 128 + k);
  }
  __syncthreads();
  float h0reg[4], h1reg[4];
  #pragma unroll
  for (int r = 0; r < 4; r++){
    h0reg[r] = bf2f(h0s[0][(m0 + r) * 136 + colw]);
    h1reg[r] = bf2f(h1s[(m0 + r) * 136 + colw]);
  }
  // prologue: pb[0]<-phi(0); gcur=gi(0); pb[1]<-phi(1); regB=phi(2)
  pb_write(pb[0], phi_ldreg(phi, b0, Tc, 0));
  __syncthreads();
  float gcur[3][4];
  {
    short8 a[4];
    #pragma unroll
    for (int ks = 0; ks < 4; ks++) a[ks] = frag_ld(pb[0] + ks * 32, 136);
    #pragma unroll
    for (int g = 0; g < 3; g++){
      f32x4 acc = zero4();
      #pragma unroll
      for (int ks = 0; ks < 4; ks++)
        acc = mfma16(a[ks], frag_ld(wi0 + (g * 128 + wv * 16) * 136 + ks * 32, 136), acc);
      #pragma unroll
      for (int r = 0; r < 4; r++) gcur[g][r] = acc[r];
    }
  }
  pb_write(pb[1], phi_ldreg(phi, b0, Tc, 1));
  uint2 regA, regB;
  regB = phi_ldreg(phi, b0, Tc, 2 < Tc ? 2 : 0);
  __syncthreads();

  // STEP: pp = t&1 (compile-time per unrolled slot).
  // ldNew <- phi(t+3) issued at top; wrVal = phi(t+2) (loaded last step) -> pb[pp] late.
  auto STEP = [&](int t, int pp, uint2& ldNew, uint2 wrVal){
    // [1] issue next prefetch (held in regs ~2 steps)
    if (t + 3 < Tc) ldNew = phi_ldreg(phi, b0, Tc, t + 3);
    // [2] Hs(t) <- h1s (h1 before step t), coalesced; fire-and-forget store
    {
      int c = threadIdx.x;
      int row = c >> 5, k = (c & 31) * 4;
      *(uint2*)(Hs + ((size_t)(b0 + row) * Tc + t) * 128 + k) =
          *(const uint2*)(h1s + row * 136 + k);
    }
    // [2a] gnxt = gi(t+1) from pb[pp^1]
    float gnxt[3][4];
    if (t + 1 < Tc){
      short8 a[4];
      #pragma unroll
      for (int ks = 0; ks < 4; ks++) a[ks] = frag_ld(pb[pp ^ 1] + ks * 32, 136);
      #pragma unroll
      for (int g = 0; g < 3; g++){
        f32x4 acc = zero4();
        #pragma unroll
        for (int ks = 0; ks < 4; ks++)
          acc = mfma16(a[ks], frag_ld(wi0 + (g * 128 + wv * 16) * 136 + ks * 32, 136), acc);
        #pragma unroll
        for (int r = 0; r < 4; r++) gnxt[g][r] = acc[r];
      }
    } else {
      #pragma unroll
      for (int g = 0; g < 3; g++)
        #pragma unroll
        for (int r = 0; r < 4; r++) gnxt[g][r] = 0.f;
    }
    // [2b] gh0 (h0s[pp]) and gh1 (h1s)
    short8 a[4];
    f32x4 gh0[3], gh1[3];
    #pragma unroll
    for (int g = 0; g < 3; g++){ gh0[g] = zero4(); gh1[g] = zero4(); }
    #pragma unroll
    for (int ks = 0; ks < 4; ks++) a[ks] = frag_ld(h0s[pp] + ks * 32, 136);
    #pragma unroll
    for (int g = 0; g < 3; g++)
      #pragma unroll
      for (int ks = 0; ks < 4; ks++)
        gh0[g] = mfma16(a[ks], wB[0][g][ks], gh0[g]);
    #pragma unroll
    for (int ks = 0; ks < 4; ks++) a[ks] = frag_ld(h1s + ks * 32, 136);
    #pragma unroll
    for (int g = 0; g < 3; g++)
      #pragma unroll
      for (int ks = 0; ks < 4; ks++)
        gh1[g] = mfma16(a[ks], wB[2][g][ks], gh1[g]);
    // [3] layer-0 gates -> h0s[pp^1]
    #pragma unroll
    for (int r = 0; r < 4; r++){
      float rg = sigm(gcur[0][r] + gh0[0][r]);
      float zg = sigm(gcur[1][r] + gh0[1][r]);
      float ng = tanhf_(gcur[2][r] + rg * gh0[2][r]);
      float hn = (1.f - zg) * ng + zg * h0reg[r];
      h0reg[r] = hn;
      h0s[pp ^ 1][(m0 + r) * 136 + colw] = f2bf(hn);
    }
    asm volatile("s_waitcnt lgkmcnt(0)" ::: "memory");
    __builtin_amdgcn_s_barrier();                 // barrier A: new h0 visible
    asm volatile("" ::: "memory");
    // [5] gi1 = h0_new @ wih1^T ; layer-1 gates -> h1s
    f32x4 gi1[3];
    #pragma unroll
    for (int g = 0; g < 3; g++) gi1[g] = zero4();
    #pragma unroll
    for (int ks = 0; ks < 4; ks++) a[ks] = frag_ld(h0s[pp ^ 1] + ks * 32, 136);
    #pragma unroll
    for (int g = 0; g < 3; g++)
      #pragma unroll
      for (int ks = 0; ks < 4; ks++)
        gi1[g] = mfma16(a[ks], wB[1][g][ks], gi1[g]);
    #pragma unroll
    for (int r = 0; r < 4; r++){
      float rg = sigm(gi1[0][r] + gh1[0][r]);
      float zg = sigm(gi1[1][r] + gh1[1][r]);
      float ng = tanhf_(gi1[2][r] + rg * gh1[2][r]);
      float hn = (1.f - zg) * ng + zg * h1reg[r];
      h1reg[r] = hn;
      h1s[(m0 + r) * 136 + colw] = f2bf(hn);
    }
    // [6] stage phi(t+2) into pb[pp]
    if (t + 2 < Tc) pb_write(pb[pp], wrVal);
    #pragma unroll
    for (int g = 0; g < 3; g++)
      #pragma unroll
      for (int r = 0; r < 4; r++) gcur[g][r] = gnxt[g][r];
    asm volatile("s_waitcnt lgkmcnt(0)" ::: "memory");
    __builtin_amdgcn_s_barrier();                 // barrier B: new h1 + pb visible
    asm volatile("" ::: "memory");
  };

  for (int t = 0; t < Tc; t += 2){
    STEP(t,     0, regA, regB);   // writes pb[0] = phi(t+2) (from regB), loads regA = phi(t+3)
    STEP(t + 1, 1, regB, regA);   // writes pb[1] = phi(t+3) (from regA), loads regB = phi(t+4)
  }
  // save state (final h0 in h0s[0] since Tc is even)
  for (int i = threadIdx.x * 4; i < 4096; i += 2048){
    int layer = i >> 11, j = i & 2047;
    int row = j >> 7, k = j & 127;
    const u16* s = (layer ? h1s : h0s[0]) + row * 136 + k;
    *(uint2*)(hst + layer * 131072 + (b0 + row) * 128 + k) = *(const uint2*)s;
  }
}

// ---------------- phase C1: dynn + x_mean/x_logvar, per-wave tiles ----------------
__global__ __launch_bounds__(512, 2) void k_c1(const u16* __restrict__ phi, const u16* __restrict__ Hs,
    const float* __restrict__ dw0, const float* __restrict__ db0,
    const float* __restrict__ dw1, const float* __restrict__ db1,
    const float* __restrict__ xmw, const float* __restrict__ xmb,
    const float* __restrict__ xlw, const float* __restrict__ xlb,
    u16* __restrict__ xmlv, int Tc){
  __shared__ __align__(16) u16 w0s[128 * 264];
  __shared__ __align__(16) u16 w1s[128 * 136];
  __shared__ __align__(16) u16 xws[32 * 136];
  __shared__ __align__(16) u16 buf[8][16 * 136];
  stage_weights(w0s, dw0, 128, 256, 256);
  stage_weights(w1s, dw1, 128, 128, 128);
  stage_weights(xws, xmw, 16, 128, 128);
  stage_weights(xws + 16 * 136, xlw, 16, 128, 128);
  int wv = threadIdx.x >> 6, l = threadIdx.x & 63;
  u16* mybuf = buf[wv];
  float b0v[8], b1v[8];
  #pragma unroll
  for (int nt = 0; nt < 8; nt++){
    b0v[nt] = db0[nt * 16 + (l & 15)];
    b1v[nt] = db1[nt * 16 + (l & 15)];
  }
  float bxm = xmb[l & 15], bxl = xlb[l & 15];
  __syncthreads();
  int tpb = Tc >> 4;
  int ntile = 1024 * tpb;
  int stride = gridDim.x * 8;
  for (int tile = blockIdx.x * 8 + wv; tile < ntile; tile += stride){
    int b = tile / tpb;
    int tt = (tile - b * tpb) << 4;
    size_t rbase = (size_t)(b * Tc + tt);
    const u16* ap = phi + rbase * 128;
    const u16* hp = Hs + rbase * 128;
    f32x4 acc[8];
    #pragma unroll
    for (int nt = 0; nt < 8; nt++) acc[nt] = zero4();
    #pragma unroll
    for (int ks = 0; ks < 8; ks++){
      short8 a = (ks < 4) ? gfrag(ap, 128, ks) : gfrag(hp, 128, ks - 4);
      #pragma unroll
      for (int nt = 0; nt < 8; nt++)
        acc[nt] = mfma16(a, frag_ld(w0s + nt * 16 * 264 + ks * 32, 264), acc[nt]);
    }
    #pragma unroll
    for (int nt = 0; nt < 8; nt++)
      acc_store_lds(mybuf, 136, nt * 16, acc[nt], b0v[nt], true);
    f32x4 a2[8];
    #pragma unroll
    for (int nt = 0; nt < 8; nt++) a2[nt] = zero4();
    #pragma unroll
    for (int ks = 0; ks < 4; ks++){
      short8 a = frag_ld(mybuf + ks * 32, 136);
      #pragma unroll
      for (int nt = 0; nt < 8; nt++)
        a2[nt] = mfma16(a, frag_ld(w1s + nt * 16 * 136 + ks * 32, 136), a2[nt]);
    }
    #pragma unroll
    for (int nt = 0; nt < 8; nt++)
      acc_store_lds(mybuf, 136, nt * 16, a2[nt], b1v[nt], false);
    f32x4 am = zero4(), al = zero4();
    #pragma unroll
    for (int ks = 0; ks < 4; ks++){
      short8 a = frag_ld(mybuf + ks * 32, 136);
      am = mfma16(a, frag_ld(xws + ks * 32, 136), am);
      al = mfma16(a, frag_ld(xws + 16 * 136 + ks * 32, 136), al);
    }
    acc_store_lds(mybuf, 136, 0, am, bxm, false);
    acc_store_lds(mybuf, 136, 16, al, bxl, false);
    u16* dst = xmlv + rbase * 32;
    int c = l;
    int row = c >> 2, k = (c & 3) * 8;
    *(short8*)(dst + row * 32 + k) = *(const short8*)(mybuf + row * 136 + k);
  }
}

// ---------------- phase C2: phi_x + menn + C@x_mean + loss, per-wave tiles ----------------
__global__ __launch_bounds__(512, 2) void k_c2(const u16* __restrict__ xmlv, const float* __restrict__ y,
    const float* __restrict__ pw0, const float* __restrict__ pb0,
    const float* __restrict__ pw1, const float* __restrict__ pb1,
    const float* __restrict__ mw0, const float* __restrict__ mb0,
    const float* __restrict__ mw1, const float* __restrict__ mb1,
    const float* __restrict__ Cw, float* __restrict__ out, int t0, int Tc){
  __shared__ __align__(16) u16 pw0s[128 * 40];
  __shared__ __align__(16) u16 pw1s[128 * 136];
  __shared__ __align__(16) u16 mw0s[128 * 136];
  __shared__ __align__(16) u16 mw1s[16 * 136];
  __shared__ __align__(16) u16 Cs[16 * 40];
  __shared__ __align__(16) u16 buf[8][16 * 136];
  stage_weights(pw0s, pw0, 128, 32, 32);
  stage_weights(pw1s, pw1, 128, 128, 128);
  stage_weights(mw0s, mw0, 128, 128, 128);
  stage_weights(mw1s, mw1, 16, 128, 128);
  stage_weights(Cs, Cw, 16, 16, 32);
  int wv = threadIdx.x >> 6, l = threadIdx.x & 63;
  u16* mybuf = buf[wv];
  float bp0v[8], bp1v[8], bm0v[8];
  #pragma unroll
  for (int nt = 0; nt < 8; nt++){
    bp0v[nt] = pb0[nt * 16 + (l & 15)];
    bp1v[nt] = pb1[nt * 16 + (l & 15)];
    bm0v[nt] = mb0[nt * 16 + (l & 15)];
  }
  float bm1 = mb1[l & 15];
  __syncthreads();
  float lacc = 0.f;
  int tpb = Tc >> 4;
  int ntile = 1024 * tpb;
  int stride = gridDim.x * 8;
  for (int tile = blockIdx.x * 8 + wv; tile < ntile; tile += stride){
    int b = tile / tpb;
    int tt = (tile - b * tpb) << 4;
    size_t rbase = (size_t)(b * Tc + tt);
    const u16* xp = xmlv + rbase * 32;
    short8 a0 = gfrag(xp, 32, 0);
    f32x4 acc[8];
    #pragma unroll
    for (int nt = 0; nt < 8; nt++)
      acc[nt] = mfma16(a0, frag_ld(pw0s + nt * 16 * 40, 40), zero4());
    #pragma unroll
    for (int nt = 0; nt < 8; nt++)
      acc_store_lds(mybuf, 136, nt * 16, acc[nt], bp0v[nt], true);
    f32x4 a2[8];
    #pragma unroll
    for (int nt = 0; nt < 8; nt++) a2[nt] = zero4();
    #pragma unroll
    for (int ks = 0; ks < 4; ks++){
      short8 a = frag_ld(mybuf + ks * 32, 136);
      #pragma unroll
      for (int nt = 0; nt < 8; nt++)
        a2[nt] = mfma16(a, frag_ld(pw1s + nt * 16 * 136 + ks * 32, 136), a2[nt]);
    }
    #pragma unroll
    for (int nt = 0; nt < 8; nt++)
      acc_store_lds(mybuf, 136, nt * 16, a2[nt], bp1v[nt], false);
    f32x4 a3[8];
    #pragma unroll
    for (int nt = 0; nt < 8; nt++) a3[nt] = zero4();
    #pragma unroll
    for (int ks = 0; ks < 4; ks++){
      short8 a = frag_ld(mybuf + ks * 32, 136);
      #pragma unroll
      for (int nt = 0; nt < 8; nt++)
        a3[nt] = mfma16(a, frag_ld(mw0s + nt * 16 * 136 + ks * 32, 136), a3[nt]);
    }
    #pragma unroll
    for (int nt = 0; nt < 8; nt++)
      acc_store_lds(mybuf, 136, nt * 16, a3[nt], bm0v[nt], true);
    f32x4 ay = zero4();
    #pragma unroll
    for (int ks = 0; ks < 4; ks++){
      short8 a = frag_ld(mybuf + ks * 32, 136);
      ay = mfma16(a, frag_ld(mw1s + ks * 32, 136), ay);
    }
    f32x4 ac = mfma16(a0, frag_ld(Cs, 40), zero4());
    #pragma unroll
    for (int r = 0; r < 4; r++){
      float yh = ay[r] + bm1 + ac[r];
      int m = (l >> 4) * 4 + r, j = l & 15;
      float d = yh - y[(size_t)(b * 16 + j) * 1024 + t0 + tt + m];
      lacc += d * d;
    }
  }
  #pragma unroll
  for (int off = 32; off > 0; off >>= 1)
    lacc += __shfl_down(lacc, off);
  if (l == 0) atomicAdd(out, lacc);
}

extern "C" void kernel_launch(void* const* d_in, const int* in_sizes, int n_in,
                              void* d_out, int out_size, void* d_ws, size_t ws_size,
                              hipStream_t stream){
  const float* u    = (const float*)d_in[0];
  const float* y    = (const float*)d_in[1];
  const float* h0   = (const float*)d_in[2];
  const float* puw0 = (const float*)d_in[3];
  const float* pub0 = (const float*)d_in[4];
  const float* puw1 = (const float*)d_in[5];
  const float* pub1 = (const float*)d_in[6];
  const float* dw0  = (const float*)d_in[7];
  const float* db0  = (const float*)d_in[8];
  const float* dw1  = (const float*)d_in[9];
  const float* db1  = (const float*)d_in[10];
  const float* xmw  = (const float*)d_in[11];
  const float* xmb  = (const float*)d_in[12];
  const float* xlw  = (const float*)d_in[13];
  const float* xlb  = (const float*)d_in[14];
  const float* pxw0 = (const float*)d_in[15];
  const float* pxb0 = (const float*)d_in[16];
  const float* pxw1 = (const float*)d_in[17];
  const float* pxb1 = (const float*)d_in[18];
  const float* mw0  = (const float*)d_in[19];
  const float* mb0  = (const float*)d_in[20];
  const float* mw1  = (const float*)d_in[21];
  const float* mb1  = (const float*)d_in[22];
  const float* gwih = (const float*)d_in[23];
  const float* gwhh = (const float*)d_in[24];
  const float* Cw   = (const float*)d_in[25];

  char* w = (char*)d_ws;
  u16* hst = (u16*)w; w += (size_t)2 * 1024 * 128 * 2;
  size_t head = (size_t)2 * 1024 * 128 * 2 + 4096;
  size_t avail = (ws_size > head) ? (ws_size - head) : 0;
  int Tc = 1024;
  while (Tc > 64 && (size_t)1024 * (size_t)Tc * (128 + 128 + 32) * 2 > avail) Tc >>= 1;
  u16* phi  = (u16*)w; w += (size_t)1024 * Tc * 128 * 2;
  u16* Hs   = (u16*)w; w += (size_t)1024 * Tc * 128 * 2;
  u16* xmlv = (u16*)w; w += (size_t)1024 * Tc * 32 * 2;

  hipMemsetAsync(d_out, 0, sizeof(float), stream);
  k_inith<<<1024, 256, 0, stream>>>(h0, hst);
  for (int t0 = 0; t0 < 1024; t0 += Tc){
    k_phiu<<<512, 512, 0, stream>>>(u, puw0, pub0, puw1, pub1, phi, t0, Tc);
    k_gru<<<64, 512, 0, stream>>>(phi, gwih, gwhh, hst, Hs, Tc);
    k_c1<<<256, 512, 0, stream>>>(phi, Hs, dw0, db0, dw1, db1, xmw, xmb, xlw, xlb, xmlv, Tc);
    k_c2<<<256, 512, 0, stream>>>(xmlv, y, pxw0, pxb0, pxw1, pxb1, mw0, mb0, mw1, mb1, Cw,
                                  (float*)d_out, t0, Tc);
  }
}